// Round 15
// baseline (575.977 us; speedup 1.0000x reference)
//
#include <hip/hip_runtime.h>
#include <math.h>

typedef unsigned short u16;
typedef unsigned int   u32;
typedef __attribute__((ext_vector_type(4))) float f32x4;
typedef __attribute__((ext_vector_type(4))) u16   u16x4;
typedef __attribute__((ext_vector_type(8))) __bf16 bf16x8;

#define AS1 __attribute__((address_space(1)))
#define AS3 __attribute__((address_space(3)))

__device__ __forceinline__ u16 f2bf(float f) {
  u32 u = __builtin_bit_cast(u32, f);
  u += 0x7fffu + ((u >> 16) & 1u);   // round-to-nearest-even
  return (u16)(u >> 16);
}

// ---------------- fused cast f32 -> bf16, all 8 tensors in one launch ----------------
struct Cast8 {
  const float *i0,*i1,*i2,*i3,*i4,*i5,*i6,*i7;
  u16 *o0,*o1,*o2,*o3,*o4,*o5,*o6,*o7;
};
__global__ void cast_all(Cast8 c) {
  const int i = blockIdx.x * 256 + threadIdx.x;
  if (i >= 7602176) return;
  const float* src = c.i0; u16* dst = c.o0; int off = i;
  if (i >= 2097152 && i < 4194304) { src = c.i1; dst = c.o1; off = i - 2097152; }
  if (i >= 4194304 && i < 5242880) { src = c.i2; dst = c.o2; off = i - 4194304; }
  if (i >= 5242880 && i < 5505024) { src = c.i3; dst = c.o3; off = i - 5242880; }
  if (i >= 5505024 && i < 5767168) { src = c.i4; dst = c.o4; off = i - 5505024; }
  if (i >= 5767168 && i < 6029312) { src = c.i5; dst = c.o5; off = i - 5767168; }
  if (i >= 6029312 && i < 6553600) { src = c.i6; dst = c.o6; off = i - 6029312; }
  if (i >= 6553600)                { src = c.i7; dst = c.o7; off = i - 6553600; }
  f32x4 v = *(const f32x4*)(src + (long)off * 4);
  u16x4 o = { f2bf(v[0]), f2bf(v[1]), f2bf(v[2]), f2bf(v[3]) };
  *(u16x4*)(dst + (long)off * 4) = o;
}

// chunked raster: 4-col super-columns over all Mt rows (B sub-panel L2-fit); Nt<4 -> row-major
__device__ __forceinline__ void raster(int local, int Nt, int Mt, int& ty, int& tx) {
  if (Nt < 4) { ty = local / Nt; tx = local - ty * Nt; return; }
  const int grp = local / (Mt * 4);
  const int rem = local - grp * (Mt * 4);
  ty = rem >> 2;
  tx = grp * 4 + (rem & 3);
}

// ---------------- specialized out-GEMM: m97 structure + XOR LDS swizzle ----------------
__launch_bounds__(256, 5)
__global__ void gemm_out(const u16* __restrict__ Ag, const u16* __restrict__ Bg,
                         const float* __restrict__ bias, float* __restrict__ C)
{
  __shared__ __align__(16) u16 As[128 * 64];
  __shared__ __align__(16) u16 Bs[128 * 64];
  const int id = blockIdx.x;
  const int tile = (id & 7) * 64 + (id >> 3);      // 512 tiles, bijective XCD swizzle
  int ty, tx; raster(tile, 16, 32, ty, tx);        // chunked raster (B sub-panel L2-fit)
  const int m0 = ty << 7, n0 = tx << 7;
  const int tid  = threadIdx.x;
  const int lane = tid & 63;
  const int wid  = tid >> 6;
  const int wm = wid >> 1, wn = wid & 1;
  const int lr = lane & 15, lg = lane >> 4;
  const int rmask = (lr & 7) << 3;

  f32x4 acc[4][4] = {};

  for (int k0 = 0; k0 < 2048; k0 += 64) {
    #pragma unroll
    for (int i = 0; i < 4; ++i) {
      const int eo = tid * 8 + i * 2048;
      const int r = eo >> 6;
      const int cs = (((tid & 7) ^ (r & 7)) << 3);
      __builtin_amdgcn_global_load_lds(
          (const AS1 void*)(Ag + (long)(m0 + r) * 2048 + k0 + cs),
          (AS3 void*)(As + eo), 16, 0, 0);
      __builtin_amdgcn_global_load_lds(
          (const AS1 void*)(Bg + (long)(n0 + r) * 2048 + k0 + cs),
          (AS3 void*)(Bs + eo), 16, 0, 0);
    }
    __syncthreads();
    #pragma unroll
    for (int kk = 0; kk < 64; kk += 32) {
      bf16x8 a4[4], b4[4];
      #pragma unroll
      for (int f = 0; f < 4; ++f)
        a4[f] = *(const bf16x8*)(As + (wm * 64 + f * 16 + lr) * 64 + ((kk + lg * 8) ^ rmask));
      #pragma unroll
      for (int f = 0; f < 4; ++f)
        b4[f] = *(const bf16x8*)(Bs + (wn * 64 + f * 16 + lr) * 64 + ((kk + lg * 8) ^ rmask));
      #pragma unroll
      for (int i = 0; i < 4; ++i)
        #pragma unroll
        for (int j = 0; j < 4; ++j)
          acc[i][j] = __builtin_amdgcn_mfma_f32_16x16x32_bf16(b4[j], a4[i], acc[i][j], 0, 0, 0);
    }
    __syncthreads();
  }

  #pragma unroll
  for (int i = 0; i < 4; ++i) {
    const int R = m0 + wm * 64 + i * 16 + lr;
    #pragma unroll
    for (int j = 0; j < 4; ++j) {
      const int cb = n0 + wn * 64 + j * 16 + lg * 4;
      f32x4 v = acc[i][j];
      f32x4 bv = *(const f32x4*)(bias + cb);
      v[0] += bv[0]; v[1] += bv[1]; v[2] += bv[2]; v[3] += bv[3];
      *(f32x4*)(C + (long)R * 2048 + cb) = v;
    }
  }
}

// ---------------- universal 128x128 2-phase NT GEMM + XOR LDS swizzle ----------------
// EPI: 0 f32 row-major; 1 bf16 row-major; 2 bf16 ->(B,H,S,128) swizzled d;
//      3 bf16 ->(B,H,128,S) swizzled s (scalar stores); 5 bf16 k-half (B-row remap, d=64..);
//      6 rope-fused -> k_ws d=0..63 swizzled
struct SubG {
  const u16* A; const u16* B; const float* bias; void* C;
  int Nt; int K; int lda; int ldb; int ldc; int EPI; int blk0;
};

__launch_bounds__(256, 5)
__global__ void gemm2(SubG g0, SubG g1, SubG g2, SubG g3, int ng, int nhalf)
{
  __shared__ __align__(16) u16 As[128 * 64];
  __shared__ __align__(16) u16 Bs[128 * 64];
  const int id = blockIdx.x;
  int tile = ((id & 7) * (gridDim.x >> 3)) + (id >> 3);   // bijective XCD swizzle (nwg%8==0)
  if (nhalf > 0) tile = (tile & 1) ? nhalf + (tile >> 1) : (tile >> 1);  // long/short mix
  SubG g = g0;
  if (ng > 1 && tile >= g1.blk0) g = g1;
  if (ng > 2 && tile >= g2.blk0) g = g2;
  if (ng > 3 && tile >= g3.blk0) g = g3;
  const int local = tile - g.blk0;
  int ty, tx; raster(local, g.Nt, 32, ty, tx);            // chunked raster
  const int m0 = ty << 7, n0 = tx << 7;

  const int tid  = threadIdx.x;
  const int lane = tid & 63;
  const int wid  = tid >> 6;
  const int wm = wid >> 1, wn = wid & 1;
  const int lr = lane & 15, lg = lane >> 4;
  const int lda = g.lda, ldb = g.ldb;
  const bool remapB = (g.EPI == 5);
  const u16* Ag = g.A;
  const u16* Bg = g.B;
  const int rmask = (lr & 7) << 3;

  f32x4 acc[4][4] = {};

  for (int k0 = 0; k0 < g.K; k0 += 64) {
    #pragma unroll
    for (int i = 0; i < 4; ++i) {
      const int eo = tid * 8 + i * 2048;
      const int r = eo >> 6;
      const int cs = (((tid & 7) ^ (r & 7)) << 3);
      __builtin_amdgcn_global_load_lds(
          (const AS1 void*)(Ag + (long)(m0 + r) * lda + (k0 + cs)),
          (AS3 void*)(As + eo), 16, 0, 0);
    }
    #pragma unroll
    for (int i = 0; i < 4; ++i) {
      const int eo = tid * 8 + i * 2048;
      const int r = eo >> 6;
      const int cs = (((tid & 7) ^ (r & 7)) << 3);
      int nr = n0 + r;
      if (remapB) nr = ((nr >> 6) << 7) + 64 + (nr & 63);
      __builtin_amdgcn_global_load_lds(
          (const AS1 void*)(Bg + (long)nr * ldb + (k0 + cs)),
          (AS3 void*)(Bs + eo), 16, 0, 0);
    }
    __syncthreads();
    #pragma unroll
    for (int kk = 0; kk < 64; kk += 32) {
      bf16x8 a4[4], b4[4];
      #pragma unroll
      for (int f = 0; f < 4; ++f)
        a4[f] = *(const bf16x8*)(As + (wm * 64 + f * 16 + lr) * 64 + ((kk + lg * 8) ^ rmask));
      #pragma unroll
      for (int f = 0; f < 4; ++f)
        b4[f] = *(const bf16x8*)(Bs + (wn * 64 + f * 16 + lr) * 64 + ((kk + lg * 8) ^ rmask));
      #pragma unroll
      for (int i = 0; i < 4; ++i)
        #pragma unroll
        for (int j = 0; j < 4; ++j)
          acc[i][j] = __builtin_amdgcn_mfma_f32_16x16x32_bf16(b4[j], a4[i], acc[i][j], 0, 0, 0);
    }
    __syncthreads();
  }

  // ---- epilogue (swapped layout: row = base+lr, cols = base+lg*4+{0..3})
  if (g.EPI == 6) {
    const int h = (n0 + wn * 64) >> 6;
    #pragma unroll
    for (int i = 0; i < 4; ++i) {
      const int R = m0 + wm * 64 + i * 16 + lr;
      const int b = R >> 9, s2 = R & 511;
      const long base = ((long)(b * 16 + h) * 512 + s2) << 7;
      const int msk = (s2 & 7) << 3;
      #pragma unroll
      for (int j = 0; j < 2; ++j) {
        const int cb = n0 + wn * 64 + j * 16 + lg * 4;
        f32x4 b1 = *(const f32x4*)(g.bias + cb);
        f32x4 b2 = *(const f32x4*)(g.bias + cb + 32);
        u16x4 o1, o2;
        #pragma unroll
        for (int rr = 0; rr < 4; ++rr) {
          const int ii = j * 16 + lg * 4 + rr;           // in [0,32)
          const float invf = __powf(10000.0f, -(float)ii * (1.0f / 32.0f));
          float sn, cs; __sincosf((float)s2 * invf, &sn, &cs);
          const float v1 = acc[i][j][rr] + b1[rr], v2 = acc[i][j + 2][rr] + b2[rr];
          o1[rr] = f2bf(v1 * cs - v2 * sn);
          o2[rr] = f2bf(v2 * cs + v1 * sn);
        }
        const int d1 = j * 16 + lg * 4, d2 = d1 + 32;
        *(u16x4*)((u16*)g.C + base + (d1 ^ msk)) = o1;
        *(u16x4*)((u16*)g.C + base + (d2 ^ msk)) = o2;
      }
    }
  } else {
    #pragma unroll
    for (int i = 0; i < 4; ++i) {
      const int R = m0 + wm * 64 + i * 16 + lr;
      #pragma unroll
      for (int j = 0; j < 4; ++j) {
        const int cb = n0 + wn * 64 + j * 16 + lg * 4;
        f32x4 v = acc[i][j];
        if (g.EPI == 0) {
          if (g.bias) {
            f32x4 bv = *(const f32x4*)(g.bias + cb);
            v[0] += bv[0]; v[1] += bv[1]; v[2] += bv[2]; v[3] += bv[3];
          }
          *(f32x4*)((float*)g.C + (long)R * g.ldc + cb) = v;
        } else if (g.EPI == 1) {
          f32x4 bv = *(const f32x4*)(g.bias + cb);
          u16x4 o = { f2bf(v[0] + bv[0]), f2bf(v[1] + bv[1]),
                      f2bf(v[2] + bv[2]), f2bf(v[3] + bv[3]) };
          *(u16x4*)((u16*)g.C + (long)R * g.ldc + cb) = o;
        } else if (g.EPI == 2) {
          f32x4 bv = *(const f32x4*)(g.bias + cb);
          const int b = R >> 9, s2 = R & 511, h = cb >> 7, d = cb & 127;
          u16x4 o = { f2bf(v[0] + bv[0]), f2bf(v[1] + bv[1]),
                      f2bf(v[2] + bv[2]), f2bf(v[3] + bv[3]) };
          *(u16x4*)((u16*)g.C + (((long)(b * 16 + h) * 512 + s2) << 7) + (d ^ ((s2 & 7) << 3))) = o;
        } else if (g.EPI == 5) {
          const int h = cb >> 6, d = 64 + (cb & 63);
          f32x4 bv = *(const f32x4*)(g.bias + h * 128 + d);
          const int b = R >> 9, s2 = R & 511;
          u16x4 o = { f2bf(v[0] + bv[0]), f2bf(v[1] + bv[1]),
                      f2bf(v[2] + bv[2]), f2bf(v[3] + bv[3]) };
          *(u16x4*)((u16*)g.C + (((long)(b * 16 + h) * 512 + s2) << 7) + (d ^ ((s2 & 7) << 3))) = o;
        } else { // EPI 3: 4 scalar stores (s-minor output, d varies per reg)
          const int b = R >> 9, s2 = R & 511;
          #pragma unroll
          for (int rr = 0; rr < 4; ++rr) {
            const int cc = cb + rr, h = cc >> 7, d = cc & 127;
            ((u16*)g.C)[(((long)(b * 16 + h) * 128 + d) << 9) + (s2 ^ ((d & 7) << 3))] =
                f2bf(v[rr] + g.bias[cc]);
          }
        }
      }
    }
  }
}

// ---------------- fused attention v2: K-dbuf (Qs-region reuse) + counted vmcnt +
//                  V0 prefetch + setprio. ----------------
__launch_bounds__(256, 2)
__global__ void fused_attn(const u16* __restrict__ qg, const u16* __restrict__ kg,
                           const u16* __restrict__ vg, float* __restrict__ attn,
                           u16* __restrict__ ctx)
{
  __shared__ __align__(16) u16 bufA[128 * 128];   // K tiles (even t), then V tiles
  __shared__ __align__(16) u16 bufB[128 * 128];   // Q (first 16KB) -> K tiles (odd t) -> Ps
  const int tid = threadIdx.x, lane = tid & 63, w = tid >> 6;
  const int lr = lane & 15, lg = lane >> 4;
  const int q0 = blockIdx.x * 64;
  const int bh = blockIdx.y;
  const u16* Qg = qg + ((long)bh * 512 + q0) * 128;
  const u16* Kg = kg + (long)bh * 65536;
  const u16* Vg = vg + (long)bh * 65536;

  auto stageK = [&](int t, u16* buf) {
    #pragma unroll
    for (int i = 0; i < 8; ++i)
      __builtin_amdgcn_global_load_lds((const AS1 void*)(Kg + t * 16384 + tid * 8 + i * 2048),
                                       (AS3 void*)(buf + tid * 8 + i * 2048), 16, 0, 0);
  };
  auto stageV = [&](int t) {
    #pragma unroll
    for (int i = 0; i < 8; ++i) {
      const int eo = tid * 8 + i * 2048;
      __builtin_amdgcn_global_load_lds((const AS1 void*)(Vg + (eo >> 7) * 512 + t * 128 + (eo & 127)),
                                       (AS3 void*)(bufA + eo), 16, 0, 0);
    }
  };

  #pragma unroll
  for (int i = 0; i < 4; ++i)
    __builtin_amdgcn_global_load_lds((const AS1 void*)(Qg + tid * 8 + i * 2048),
                                     (AS3 void*)(bufB + tid * 8 + i * 2048), 16, 0, 0);
  stageK(0, bufA);
  __syncthreads();

  bf16x8 qa[4];
  const int arow = 16 * w + lr;
  const int amsk = (lr & 7) << 3;
  #pragma unroll
  for (int kc = 0; kc < 4; ++kc)
    qa[kc] = *(const bf16x8*)(bufB + arow * 128 + ((kc * 32 + lg * 8) ^ amsk));
  asm volatile("s_waitcnt lgkmcnt(0)" ::: "memory");
  __builtin_amdgcn_s_barrier();                    // Qs dead -> bufB reusable
  stageK(1, bufB);

  f32x4 acc[32] = {};
  #pragma unroll
  for (int t = 0; t < 4; ++t) {
    const u16* KV = (t & 1) ? bufB : bufA;
    __builtin_amdgcn_s_setprio(1);
    #pragma unroll
    for (int nf = 0; nf < 8; ++nf) {
      const int n = nf * 16 + lr;
      const int nmsk = (n & 7) << 3;
      #pragma unroll
      for (int kc = 0; kc < 4; ++kc) {
        bf16x8 bb = *(const bf16x8*)(KV + n * 128 + ((kc * 32 + lg * 8) ^ nmsk));
        acc[t * 8 + nf] = __builtin_amdgcn_mfma_f32_16x16x32_bf16(bb, qa[kc], acc[t * 8 + nf], 0, 0, 0);
      }
    }
    __builtin_amdgcn_s_setprio(0);
    asm volatile("s_waitcnt lgkmcnt(0)" ::: "memory");
    __builtin_amdgcn_s_barrier();
    if (t < 3) {
      if (t + 2 < 4) {
        stageK(t + 2, (t & 1) ? bufB : bufA);
        asm volatile("s_waitcnt vmcnt(8)" ::: "memory");
      } else {
        asm volatile("s_waitcnt vmcnt(0)" ::: "memory");
      }
      __builtin_amdgcn_s_barrier();
      if (t == 2) stageV(0);
    }
  }

  const float scale = 0.08838834764831845f;
  float m_ = -1e30f;
  #pragma unroll
  for (int f = 0; f < 32; ++f)
    #pragma unroll
    for (int r = 0; r < 4; ++r) m_ = fmaxf(m_, acc[f][r]);
  m_ = fmaxf(m_, __shfl_xor(m_, 16));
  m_ = fmaxf(m_, __shfl_xor(m_, 32));
  float s_ = 0.f;
  #pragma unroll
  for (int f = 0; f < 32; ++f)
    #pragma unroll
    for (int r = 0; r < 4; ++r) {
      const float e = __expf((acc[f][r] - m_) * scale);
      acc[f][r] = e; s_ += e;
    }
  s_ += __shfl_xor(s_, 16);
  s_ += __shfl_xor(s_, 32);
  const float inv = 1.0f / s_;
  #pragma unroll
  for (int f = 0; f < 32; ++f)
    #pragma unroll
    for (int r = 0; r < 4; ++r) acc[f][r] *= inv;

  {
    float* arow_p = attn + ((long)bh * 512 + q0 + 16 * w + lr) * 512;
    #pragma unroll
    for (int t = 0; t < 4; ++t)
      #pragma unroll
      for (int gg = 0; gg < 8; ++gg)
        *(f32x4*)(arow_p + t * 128 + gg * 16 + lg * 4) = acc[t * 8 + gg];
  }

  f32x4 ctxa[8] = {};
  #pragma unroll
  for (int t = 0; t < 4; ++t) {
    #pragma unroll
    for (int gg = 0; gg < 8; ++gg) {
      const int col = gg * 16 + lg * 4;
      u16x4 o = { f2bf(acc[t * 8 + gg][0]), f2bf(acc[t * 8 + gg][1]),
                  f2bf(acc[t * 8 + gg][2]), f2bf(acc[t * 8 + gg][3]) };
      *(u16x4*)(bufB + arow * 128 + (col ^ amsk)) = o;
    }
    if (t > 0) stageV(t);
    __syncthreads();
    bf16x8 pa[4];
    #pragma unroll
    for (int kc = 0; kc < 4; ++kc)
      pa[kc] = *(const bf16x8*)(bufB + arow * 128 + ((kc * 32 + lg * 8) ^ amsk));
    __builtin_amdgcn_s_setprio(1);
    #pragma unroll
    for (int nf = 0; nf < 8; ++nf) {
      const int n = nf * 16 + lr;
      const int nmsk = (n & 7) << 3;
      #pragma unroll
      for (int kc = 0; kc < 4; ++kc) {
        bf16x8 vb = *(const bf16x8*)(bufA + n * 128 + ((kc * 32 + lg * 8) ^ nmsk));
        ctxa[nf] = __builtin_amdgcn_mfma_f32_16x16x32_bf16(vb, pa[kc], ctxa[nf], 0, 0, 0);
      }
    }
    __builtin_amdgcn_s_setprio(0);
    __syncthreads();
  }

  const int b = bh >> 4, h = bh & 15;
  u16* crow = ctx + (long)(b * 512 + q0 + 16 * w + lr) * 2048 + h * 128;
  #pragma unroll
  for (int nf = 0; nf < 8; ++nf) {
    u16x4 o = { f2bf(ctxa[nf][0]), f2bf(ctxa[nf][1]),
                f2bf(ctxa[nf][2]), f2bf(ctxa[nf][3]) };
    *(u16x4*)(crow + nf * 16 + lg * 4) = o;
  }
}

extern "C" void kernel_launch(void* const* d_in, const int* in_sizes, int n_in,
                              void* d_out, int out_size, void* d_ws, size_t ws_size,
                              hipStream_t stream)
{
  (void)in_sizes; (void)n_in; (void)out_size; (void)ws_size;
  const float* query  = (const float*)d_in[0];
  const float* kvin   = (const float*)d_in[1];
  const float* wq_w   = (const float*)d_in[2];
  const float* wq_b   = (const float*)d_in[3];
  const float* wdkv_w = (const float*)d_in[4];
  const float* wdkv_b = (const float*)d_in[5];
  const float* wupk_w = (const float*)d_in[6];
  const float* wupk_b = (const float*)d_in[7];
  const float* wupv_w = (const float*)d_in[8];
  const float* wupv_b = (const float*)d_in[9];
  const float* wkr_w  = (const float*)d_in[10];
  const float* wkr_b  = (const float*)d_in[11];
  const float* wo_w   = (const float*)d_in[12];
  const float* wo_b   = (const float*)d_in[13];

  float* out  = (float*)d_out;                 // (8,512,2048)
  float* attn = out + 8L * 512 * 2048;         // (8,16,512,512)

  u16* p = (u16*)d_ws;
  u16* query_bf = p; p += 8388608;
  u16* kv_bf    = p; p += 8388608;
  u16* wq_bf    = p; p += 4194304;
  u16* wdkv_bf  = p; p += 1048576;
  u16* wupk_bf  = p; p += 1048576;
  u16* wupv_bf  = p; p += 1048576;
  u16* wkr_bf   = p; p += 2097152;
  u16* wo_bf    = p; p += 4194304;
  u16* q_ws     = p; p += 8388608;   // (B,H,S,128) bf16, swizzled
  u16* ckv_bf   = p; p += 2097152;   // (4096,512) bf16
  u16* k_ws     = p; p += 8388608;   // (B,H,S,128) bf16, swizzled
  u16* vT_ws    = p; p += 8388608;   // (B,H,128,S) bf16, swizzled
  u16* ctx_ws   = p; p += 8388608;   // (B,S,H*128) bf16

  Cast8 c8 = { query, kvin, wq_w, wdkv_w, wupk_w, wupv_w, wkr_w, wo_w,
               query_bf, kv_bf, wq_bf, wdkv_bf, wupk_bf, wupv_bf, wkr_bf, wo_bf };
  cast_all<<<dim3(29696), dim3(256), 0, stream>>>(c8);

  // c_kv = kv @ wdkv^T + b -> bf16 (4096,512): 128 tiles (Nt=4)
  SubG gc = { kv_bf, wdkv_bf, wdkv_b, ckv_bf, 4, 2048, 2048, 2048, 512, 1, 0 };
  gemm2<<<dim3(128), dim3(256), 0, stream>>>(gc, gc, gc, gc, 1, 0);

  // mega: q(EPI2, 512t) + rope-fused(EPI6, 256t) long; k_up(EPI5, 256t) + v_up(EPI3, 512t) short
  SubG gq = { query_bf, wq_bf,   wq_b,   q_ws, 16, 2048, 2048, 2048, 0, 2, 0    };
  SubG gr = { kv_bf,    wkr_bf,  wkr_b,  k_ws, 8,  2048, 2048, 2048, 0, 6, 512  };
  SubG gk = { ckv_bf,   wupk_bf, wupk_b, k_ws, 8,  512,  512,  512,  0, 5, 768  };
  SubG gv = { ckv_bf,   wupv_bf, wupv_b, vT_ws,16, 512,  512,  512,  0, 3, 1024 };
  gemm2<<<dim3(1536), dim3(256), 0, stream>>>(gq, gr, gk, gv, 4, 768);

  // fused attention: scores + softmax + attn write + PV -> ctx_ws
  fused_attn<<<dim3(8, 128, 1), 256, 0, stream>>>(q_ws, k_ws, vT_ws, attn, ctx_ws);

  // out = ctx @ wo^T + b -> f32: specialized kernel + swizzle, 512 tiles
  gemm_out<<<dim3(512), dim3(256), 0, stream>>>(ctx_ws, wo_bf, wo_b, out);
}

// Round 16
// 277.675 us; speedup vs baseline: 2.0743x; 2.0743x over previous
//
#include <hip/hip_runtime.h>
#include <math.h>

typedef unsigned short u16;
typedef unsigned int   u32;
typedef __attribute__((ext_vector_type(4))) float f32x4;
typedef __attribute__((ext_vector_type(4))) u16   u16x4;
typedef __attribute__((ext_vector_type(8))) __bf16 bf16x8;

#define AS1 __attribute__((address_space(1)))
#define AS3 __attribute__((address_space(3)))

__device__ __forceinline__ u16 f2bf(float f) {
  u32 u = __builtin_bit_cast(u32, f);
  u += 0x7fffu + ((u >> 16) & 1u);   // round-to-nearest-even
  return (u16)(u >> 16);
}

// ---------------- fused cast f32 -> bf16, all 8 tensors in one launch ----------------
struct Cast8 {
  const float *i0,*i1,*i2,*i3,*i4,*i5,*i6,*i7;
  u16 *o0,*o1,*o2,*o3,*o4,*o5,*o6,*o7;
};
__global__ void cast_all(Cast8 c) {
  const int i = blockIdx.x * 256 + threadIdx.x;
  if (i >= 7602176) return;
  const float* src = c.i0; u16* dst = c.o0; int off = i;
  if (i >= 2097152 && i < 4194304) { src = c.i1; dst = c.o1; off = i - 2097152; }
  if (i >= 4194304 && i < 5242880) { src = c.i2; dst = c.o2; off = i - 4194304; }
  if (i >= 5242880 && i < 5505024) { src = c.i3; dst = c.o3; off = i - 5242880; }
  if (i >= 5505024 && i < 5767168) { src = c.i4; dst = c.o4; off = i - 5505024; }
  if (i >= 5767168 && i < 6029312) { src = c.i5; dst = c.o5; off = i - 5767168; }
  if (i >= 6029312 && i < 6553600) { src = c.i6; dst = c.o6; off = i - 6029312; }
  if (i >= 6553600)                { src = c.i7; dst = c.o7; off = i - 6553600; }
  f32x4 v = *(const f32x4*)(src + (long)off * 4);
  u16x4 o = { f2bf(v[0]), f2bf(v[1]), f2bf(v[2]), f2bf(v[3]) };
  *(u16x4*)(dst + (long)off * 4) = o;
}

// chunked raster: 4-col super-columns over all Mt rows (B sub-panel L2-fit); Nt<4 -> row-major
__device__ __forceinline__ void raster(int local, int Nt, int Mt, int& ty, int& tx) {
  if (Nt < 4) { ty = local / Nt; tx = local - ty * Nt; return; }
  const int grp = local / (Mt * 4);
  const int rem = local - grp * (Mt * 4);
  ty = rem >> 2;
  tx = grp * 4 + (rem & 3);
}

// ---------------- specialized out-GEMM: m97 structure + XOR LDS swizzle ----------------
__launch_bounds__(256, 4)
__global__ void gemm_out(const u16* __restrict__ Ag, const u16* __restrict__ Bg,
                         const float* __restrict__ bias, float* __restrict__ C)
{
  __shared__ __align__(16) u16 As[128 * 64];
  __shared__ __align__(16) u16 Bs[128 * 64];
  const int id = blockIdx.x;
  const int tile = (id & 7) * 64 + (id >> 3);      // 512 tiles, bijective XCD swizzle
  int ty, tx; raster(tile, 16, 32, ty, tx);        // chunked raster (B sub-panel L2-fit)
  const int m0 = ty << 7, n0 = tx << 7;
  const int tid  = threadIdx.x;
  const int lane = tid & 63;
  const int wid  = tid >> 6;
  const int wm = wid >> 1, wn = wid & 1;
  const int lr = lane & 15, lg = lane >> 4;
  const int rmask = (lr & 7) << 3;

  f32x4 acc[4][4] = {};

  for (int k0 = 0; k0 < 2048; k0 += 64) {
    #pragma unroll
    for (int i = 0; i < 4; ++i) {
      const int eo = tid * 8 + i * 2048;
      const int r = eo >> 6;
      const int cs = (((tid & 7) ^ (r & 7)) << 3);
      __builtin_amdgcn_global_load_lds(
          (const AS1 void*)(Ag + (long)(m0 + r) * 2048 + k0 + cs),
          (AS3 void*)(As + eo), 16, 0, 0);
      __builtin_amdgcn_global_load_lds(
          (const AS1 void*)(Bg + (long)(n0 + r) * 2048 + k0 + cs),
          (AS3 void*)(Bs + eo), 16, 0, 0);
    }
    __syncthreads();
    #pragma unroll
    for (int kk = 0; kk < 64; kk += 32) {
      bf16x8 a4[4], b4[4];
      #pragma unroll
      for (int f = 0; f < 4; ++f)
        a4[f] = *(const bf16x8*)(As + (wm * 64 + f * 16 + lr) * 64 + ((kk + lg * 8) ^ rmask));
      #pragma unroll
      for (int f = 0; f < 4; ++f)
        b4[f] = *(const bf16x8*)(Bs + (wn * 64 + f * 16 + lr) * 64 + ((kk + lg * 8) ^ rmask));
      #pragma unroll
      for (int i = 0; i < 4; ++i)
        #pragma unroll
        for (int j = 0; j < 4; ++j)
          acc[i][j] = __builtin_amdgcn_mfma_f32_16x16x32_bf16(b4[j], a4[i], acc[i][j], 0, 0, 0);
    }
    __syncthreads();
  }

  #pragma unroll
  for (int i = 0; i < 4; ++i) {
    const int R = m0 + wm * 64 + i * 16 + lr;
    #pragma unroll
    for (int j = 0; j < 4; ++j) {
      const int cb = n0 + wn * 64 + j * 16 + lg * 4;
      f32x4 v = acc[i][j];
      f32x4 bv = *(const f32x4*)(bias + cb);
      v[0] += bv[0]; v[1] += bv[1]; v[2] += bv[2]; v[3] += bv[3];
      *(f32x4*)(C + (long)R * 2048 + cb) = v;
    }
  }
}

// ---------------- universal 128x128 2-phase NT GEMM + XOR LDS swizzle ----------------
// EPI: 0 f32 row-major; 1 bf16 row-major; 2 bf16 ->(B,H,S,128) swizzled d;
//      3 bf16 ->(B,H,128,S) swizzled s (scalar stores); 5 bf16 k-half (B-row remap, d=64..);
//      6 rope-fused -> k_ws d=0..63 swizzled
struct SubG {
  const u16* A; const u16* B; const float* bias; void* C;
  int Nt; int K; int lda; int ldb; int ldc; int EPI; int blk0;
};

__launch_bounds__(256, 4)
__global__ void gemm2(SubG g0, SubG g1, SubG g2, SubG g3, int ng, int nhalf)
{
  __shared__ __align__(16) u16 As[128 * 64];
  __shared__ __align__(16) u16 Bs[128 * 64];
  const int id = blockIdx.x;
  int tile = ((id & 7) * (gridDim.x >> 3)) + (id >> 3);   // bijective XCD swizzle (nwg%8==0)
  if (nhalf > 0) tile = (tile & 1) ? nhalf + (tile >> 1) : (tile >> 1);  // long/short mix
  SubG g = g0;
  if (ng > 1 && tile >= g1.blk0) g = g1;
  if (ng > 2 && tile >= g2.blk0) g = g2;
  if (ng > 3 && tile >= g3.blk0) g = g3;
  const int local = tile - g.blk0;
  int ty, tx; raster(local, g.Nt, 32, ty, tx);            // chunked raster
  const int m0 = ty << 7, n0 = tx << 7;

  const int tid  = threadIdx.x;
  const int lane = tid & 63;
  const int wid  = tid >> 6;
  const int wm = wid >> 1, wn = wid & 1;
  const int lr = lane & 15, lg = lane >> 4;
  const int lda = g.lda, ldb = g.ldb;
  const bool remapB = (g.EPI == 5);
  const u16* Ag = g.A;
  const u16* Bg = g.B;
  const int rmask = (lr & 7) << 3;

  f32x4 acc[4][4] = {};

  for (int k0 = 0; k0 < g.K; k0 += 64) {
    #pragma unroll
    for (int i = 0; i < 4; ++i) {
      const int eo = tid * 8 + i * 2048;
      const int r = eo >> 6;
      const int cs = (((tid & 7) ^ (r & 7)) << 3);
      __builtin_amdgcn_global_load_lds(
          (const AS1 void*)(Ag + (long)(m0 + r) * lda + (k0 + cs)),
          (AS3 void*)(As + eo), 16, 0, 0);
    }
    #pragma unroll
    for (int i = 0; i < 4; ++i) {
      const int eo = tid * 8 + i * 2048;
      const int r = eo >> 6;
      const int cs = (((tid & 7) ^ (r & 7)) << 3);
      int nr = n0 + r;
      if (remapB) nr = ((nr >> 6) << 7) + 64 + (nr & 63);
      __builtin_amdgcn_global_load_lds(
          (const AS1 void*)(Bg + (long)nr * ldb + (k0 + cs)),
          (AS3 void*)(Bs + eo), 16, 0, 0);
    }
    __syncthreads();
    #pragma unroll
    for (int kk = 0; kk < 64; kk += 32) {
      bf16x8 a4[4], b4[4];
      #pragma unroll
      for (int f = 0; f < 4; ++f)
        a4[f] = *(const bf16x8*)(As + (wm * 64 + f * 16 + lr) * 64 + ((kk + lg * 8) ^ rmask));
      #pragma unroll
      for (int f = 0; f < 4; ++f)
        b4[f] = *(const bf16x8*)(Bs + (wn * 64 + f * 16 + lr) * 64 + ((kk + lg * 8) ^ rmask));
      #pragma unroll
      for (int i = 0; i < 4; ++i)
        #pragma unroll
        for (int j = 0; j < 4; ++j)
          acc[i][j] = __builtin_amdgcn_mfma_f32_16x16x32_bf16(b4[j], a4[i], acc[i][j], 0, 0, 0);
    }
    __syncthreads();
  }

  // ---- epilogue (swapped layout: row = base+lr, cols = base+lg*4+{0..3})
  if (g.EPI == 6) {
    const int h = (n0 + wn * 64) >> 6;
    #pragma unroll
    for (int i = 0; i < 4; ++i) {
      const int R = m0 + wm * 64 + i * 16 + lr;
      const int b = R >> 9, s2 = R & 511;
      const long base = ((long)(b * 16 + h) * 512 + s2) << 7;
      const int msk = (s2 & 7) << 3;
      #pragma unroll
      for (int j = 0; j < 2; ++j) {
        const int cb = n0 + wn * 64 + j * 16 + lg * 4;
        f32x4 b1 = *(const f32x4*)(g.bias + cb);
        f32x4 b2 = *(const f32x4*)(g.bias + cb + 32);
        u16x4 o1, o2;
        #pragma unroll
        for (int rr = 0; rr < 4; ++rr) {
          const int ii = j * 16 + lg * 4 + rr;           // in [0,32)
          const float invf = __powf(10000.0f, -(float)ii * (1.0f / 32.0f));
          float sn, cs; __sincosf((float)s2 * invf, &sn, &cs);
          const float v1 = acc[i][j][rr] + b1[rr], v2 = acc[i][j + 2][rr] + b2[rr];
          o1[rr] = f2bf(v1 * cs - v2 * sn);
          o2[rr] = f2bf(v2 * cs + v1 * sn);
        }
        const int d1 = j * 16 + lg * 4, d2 = d1 + 32;
        *(u16x4*)((u16*)g.C + base + (d1 ^ msk)) = o1;
        *(u16x4*)((u16*)g.C + base + (d2 ^ msk)) = o2;
      }
    }
  } else {
    #pragma unroll
    for (int i = 0; i < 4; ++i) {
      const int R = m0 + wm * 64 + i * 16 + lr;
      #pragma unroll
      for (int j = 0; j < 4; ++j) {
        const int cb = n0 + wn * 64 + j * 16 + lg * 4;
        f32x4 v = acc[i][j];
        if (g.EPI == 0) {
          if (g.bias) {
            f32x4 bv = *(const f32x4*)(g.bias + cb);
            v[0] += bv[0]; v[1] += bv[1]; v[2] += bv[2]; v[3] += bv[3];
          }
          *(f32x4*)((float*)g.C + (long)R * g.ldc + cb) = v;
        } else if (g.EPI == 1) {
          f32x4 bv = *(const f32x4*)(g.bias + cb);
          u16x4 o = { f2bf(v[0] + bv[0]), f2bf(v[1] + bv[1]),
                      f2bf(v[2] + bv[2]), f2bf(v[3] + bv[3]) };
          *(u16x4*)((u16*)g.C + (long)R * g.ldc + cb) = o;
        } else if (g.EPI == 2) {
          f32x4 bv = *(const f32x4*)(g.bias + cb);
          const int b = R >> 9, s2 = R & 511, h = cb >> 7, d = cb & 127;
          u16x4 o = { f2bf(v[0] + bv[0]), f2bf(v[1] + bv[1]),
                      f2bf(v[2] + bv[2]), f2bf(v[3] + bv[3]) };
          *(u16x4*)((u16*)g.C + (((long)(b * 16 + h) * 512 + s2) << 7) + (d ^ ((s2 & 7) << 3))) = o;
        } else if (g.EPI == 5) {
          const int h = cb >> 6, d = 64 + (cb & 63);
          f32x4 bv = *(const f32x4*)(g.bias + h * 128 + d);
          const int b = R >> 9, s2 = R & 511;
          u16x4 o = { f2bf(v[0] + bv[0]), f2bf(v[1] + bv[1]),
                      f2bf(v[2] + bv[2]), f2bf(v[3] + bv[3]) };
          *(u16x4*)((u16*)g.C + (((long)(b * 16 + h) * 512 + s2) << 7) + (d ^ ((s2 & 7) << 3))) = o;
        } else { // EPI 3: 4 scalar stores (s-minor output, d varies per reg)
          const int b = R >> 9, s2 = R & 511;
          #pragma unroll
          for (int rr = 0; rr < 4; ++rr) {
            const int cc = cb + rr, h = cc >> 7, d = cc & 127;
            ((u16*)g.C)[(((long)(b * 16 + h) * 128 + d) << 9) + (s2 ^ ((d & 7) << 3))] =
                f2bf(v[rr] + g.bias[cc]);
          }
        }
      }
    }
  }
}

// ---------------- fused attention v2: K-dbuf (Qs-region reuse) + counted vmcnt +
//                  V0 prefetch + setprio. ----------------
__launch_bounds__(256, 2)
__global__ void fused_attn(const u16* __restrict__ qg, const u16* __restrict__ kg,
                           const u16* __restrict__ vg, float* __restrict__ attn,
                           u16* __restrict__ ctx)
{
  __shared__ __align__(16) u16 bufA[128 * 128];   // K tiles (even t), then V tiles
  __shared__ __align__(16) u16 bufB[128 * 128];   // Q (first 16KB) -> K tiles (odd t) -> Ps
  const int tid = threadIdx.x, lane = tid & 63, w = tid >> 6;
  const int lr = lane & 15, lg = lane >> 4;
  const int q0 = blockIdx.x * 64;
  const int bh = blockIdx.y;
  const u16* Qg = qg + ((long)bh * 512 + q0) * 128;
  const u16* Kg = kg + (long)bh * 65536;
  const u16* Vg = vg + (long)bh * 65536;

  auto stageK = [&](int t, u16* buf) {
    #pragma unroll
    for (int i = 0; i < 8; ++i)
      __builtin_amdgcn_global_load_lds((const AS1 void*)(Kg + t * 16384 + tid * 8 + i * 2048),
                                       (AS3 void*)(buf + tid * 8 + i * 2048), 16, 0, 0);
  };
  auto stageV = [&](int t) {
    #pragma unroll
    for (int i = 0; i < 8; ++i) {
      const int eo = tid * 8 + i * 2048;
      __builtin_amdgcn_global_load_lds((const AS1 void*)(Vg + (eo >> 7) * 512 + t * 128 + (eo & 127)),
                                       (AS3 void*)(bufA + eo), 16, 0, 0);
    }
  };

  #pragma unroll
  for (int i = 0; i < 4; ++i)
    __builtin_amdgcn_global_load_lds((const AS1 void*)(Qg + tid * 8 + i * 2048),
                                     (AS3 void*)(bufB + tid * 8 + i * 2048), 16, 0, 0);
  stageK(0, bufA);
  __syncthreads();

  bf16x8 qa[4];
  const int arow = 16 * w + lr;
  const int amsk = (lr & 7) << 3;
  #pragma unroll
  for (int kc = 0; kc < 4; ++kc)
    qa[kc] = *(const bf16x8*)(bufB + arow * 128 + ((kc * 32 + lg * 8) ^ amsk));
  asm volatile("s_waitcnt lgkmcnt(0)" ::: "memory");
  __builtin_amdgcn_s_barrier();                    // Qs dead -> bufB reusable
  stageK(1, bufB);

  f32x4 acc[32] = {};
  #pragma unroll
  for (int t = 0; t < 4; ++t) {
    const u16* KV = (t & 1) ? bufB : bufA;
    __builtin_amdgcn_s_setprio(1);
    #pragma unroll
    for (int nf = 0; nf < 8; ++nf) {
      const int n = nf * 16 + lr;
      const int nmsk = (n & 7) << 3;
      #pragma unroll
      for (int kc = 0; kc < 4; ++kc) {
        bf16x8 bb = *(const bf16x8*)(KV + n * 128 + ((kc * 32 + lg * 8) ^ nmsk));
        acc[t * 8 + nf] = __builtin_amdgcn_mfma_f32_16x16x32_bf16(bb, qa[kc], acc[t * 8 + nf], 0, 0, 0);
      }
    }
    __builtin_amdgcn_s_setprio(0);
    asm volatile("s_waitcnt lgkmcnt(0)" ::: "memory");
    __builtin_amdgcn_s_barrier();
    if (t < 3) {
      if (t + 2 < 4) {
        stageK(t + 2, (t & 1) ? bufB : bufA);
        asm volatile("s_waitcnt vmcnt(8)" ::: "memory");
      } else {
        asm volatile("s_waitcnt vmcnt(0)" ::: "memory");
      }
      __builtin_amdgcn_s_barrier();
      if (t == 2) stageV(0);
    }
  }

  const float scale = 0.08838834764831845f;
  float m_ = -1e30f;
  #pragma unroll
  for (int f = 0; f < 32; ++f)
    #pragma unroll
    for (int r = 0; r < 4; ++r) m_ = fmaxf(m_, acc[f][r]);
  m_ = fmaxf(m_, __shfl_xor(m_, 16));
  m_ = fmaxf(m_, __shfl_xor(m_, 32));
  float s_ = 0.f;
  #pragma unroll
  for (int f = 0; f < 32; ++f)
    #pragma unroll
    for (int r = 0; r < 4; ++r) {
      const float e = __expf((acc[f][r] - m_) * scale);
      acc[f][r] = e; s_ += e;
    }
  s_ += __shfl_xor(s_, 16);
  s_ += __shfl_xor(s_, 32);
  const float inv = 1.0f / s_;
  #pragma unroll
  for (int f = 0; f < 32; ++f)
    #pragma unroll
    for (int r = 0; r < 4; ++r) acc[f][r] *= inv;

  {
    float* arow_p = attn + ((long)bh * 512 + q0 + 16 * w + lr) * 512;
    #pragma unroll
    for (int t = 0; t < 4; ++t)
      #pragma unroll
      for (int gg = 0; gg < 8; ++gg)
        *(f32x4*)(arow_p + t * 128 + gg * 16 + lg * 4) = acc[t * 8 + gg];
  }

  f32x4 ctxa[8] = {};
  #pragma unroll
  for (int t = 0; t < 4; ++t) {
    #pragma unroll
    for (int gg = 0; gg < 8; ++gg) {
      const int col = gg * 16 + lg * 4;
      u16x4 o = { f2bf(acc[t * 8 + gg][0]), f2bf(acc[t * 8 + gg][1]),
                  f2bf(acc[t * 8 + gg][2]), f2bf(acc[t * 8 + gg][3]) };
      *(u16x4*)(bufB + arow * 128 + (col ^ amsk)) = o;
    }
    if (t > 0) stageV(t);
    __syncthreads();
    bf16x8 pa[4];
    #pragma unroll
    for (int kc = 0; kc < 4; ++kc)
      pa[kc] = *(const bf16x8*)(bufB + arow * 128 + ((kc * 32 + lg * 8) ^ amsk));
    __builtin_amdgcn_s_setprio(1);
    #pragma unroll
    for (int nf = 0; nf < 8; ++nf) {
      const int n = nf * 16 + lr;
      const int nmsk = (n & 7) << 3;
      #pragma unroll
      for (int kc = 0; kc < 4; ++kc) {
        bf16x8 vb = *(const bf16x8*)(bufA + n * 128 + ((kc * 32 + lg * 8) ^ nmsk));
        ctxa[nf] = __builtin_amdgcn_mfma_f32_16x16x32_bf16(vb, pa[kc], ctxa[nf], 0, 0, 0);
      }
    }
    __builtin_amdgcn_s_setprio(0);
    __syncthreads();
  }

  const int b = bh >> 4, h = bh & 15;
  u16* crow = ctx + (long)(b * 512 + q0 + 16 * w + lr) * 2048 + h * 128;
  #pragma unroll
  for (int nf = 0; nf < 8; ++nf) {
    u16x4 o = { f2bf(ctxa[nf][0]), f2bf(ctxa[nf][1]),
                f2bf(ctxa[nf][2]), f2bf(ctxa[nf][3]) };
    *(u16x4*)(crow + nf * 16 + lg * 4) = o;
  }
}

extern "C" void kernel_launch(void* const* d_in, const int* in_sizes, int n_in,
                              void* d_out, int out_size, void* d_ws, size_t ws_size,
                              hipStream_t stream)
{
  (void)in_sizes; (void)n_in; (void)out_size; (void)ws_size;
  const float* query  = (const float*)d_in[0];
  const float* kvin   = (const float*)d_in[1];
  const float* wq_w   = (const float*)d_in[2];
  const float* wq_b   = (const float*)d_in[3];
  const float* wdkv_w = (const float*)d_in[4];
  const float* wdkv_b = (const float*)d_in[5];
  const float* wupk_w = (const float*)d_in[6];
  const float* wupk_b = (const float*)d_in[7];
  const float* wupv_w = (const float*)d_in[8];
  const float* wupv_b = (const float*)d_in[9];
  const float* wkr_w  = (const float*)d_in[10];
  const float* wkr_b  = (const float*)d_in[11];
  const float* wo_w   = (const float*)d_in[12];
  const float* wo_b   = (const float*)d_in[13];

  float* out  = (float*)d_out;                 // (8,512,2048)
  float* attn = out + 8L * 512 * 2048;         // (8,16,512,512)

  u16* p = (u16*)d_ws;
  u16* query_bf = p; p += 8388608;
  u16* kv_bf    = p; p += 8388608;
  u16* wq_bf    = p; p += 4194304;
  u16* wdkv_bf  = p; p += 1048576;
  u16* wupk_bf  = p; p += 1048576;
  u16* wupv_bf  = p; p += 1048576;
  u16* wkr_bf   = p; p += 2097152;
  u16* wo_bf    = p; p += 4194304;
  u16* q_ws     = p; p += 8388608;   // (B,H,S,128) bf16, swizzled
  u16* ckv_bf   = p; p += 2097152;   // (4096,512) bf16
  u16* k_ws     = p; p += 8388608;   // (B,H,S,128) bf16, swizzled
  u16* vT_ws    = p; p += 8388608;   // (B,H,128,S) bf16, swizzled
  u16* ctx_ws   = p; p += 8388608;   // (B,S,H*128) bf16

  Cast8 c8 = { query, kvin, wq_w, wdkv_w, wupk_w, wupv_w, wkr_w, wo_w,
               query_bf, kv_bf, wq_bf, wdkv_bf, wupk_bf, wupv_bf, wkr_bf, wo_bf };
  cast_all<<<dim3(29696), dim3(256), 0, stream>>>(c8);

  // c_kv = kv @ wdkv^T + b -> bf16 (4096,512): 128 tiles (Nt=4)
  SubG gc = { kv_bf, wdkv_bf, wdkv_b, ckv_bf, 4, 2048, 2048, 2048, 512, 1, 0 };
  gemm2<<<dim3(128), dim3(256), 0, stream>>>(gc, gc, gc, gc, 1, 0);

  // mega: q(EPI2, 512t) + rope-fused(EPI6, 256t) long; k_up(EPI5, 256t) + v_up(EPI3, 512t) short
  SubG gq = { query_bf, wq_bf,   wq_b,   q_ws, 16, 2048, 2048, 2048, 0, 2, 0    };
  SubG gr = { kv_bf,    wkr_bf,  wkr_b,  k_ws, 8,  2048, 2048, 2048, 0, 6, 512  };
  SubG gk = { ckv_bf,   wupk_bf, wupk_b, k_ws, 8,  512,  512,  512,  0, 5, 768  };
  SubG gv = { ckv_bf,   wupv_bf, wupv_b, vT_ws,16, 512,  512,  512,  0, 3, 1024 };
  gemm2<<<dim3(1536), dim3(256), 0, stream>>>(gq, gr, gk, gv, 4, 768);

  // fused attention: scores + softmax + attn write + PV -> ctx_ws
  fused_attn<<<dim3(8, 128, 1), 256, 0, stream>>>(q_ws, k_ws, vT_ws, attn, ctx_ws);

  // out = ctx @ wo^T + b -> f32: specialized kernel + swizzle, 512 tiles
  gemm_out<<<dim3(512), dim3(256), 0, stream>>>(ctx_ws, wo_bf, wo_b, out);
}

// Round 17
// 243.332 us; speedup vs baseline: 2.3670x; 1.1411x over previous
//
#include <hip/hip_runtime.h>
#include <math.h>

typedef unsigned short u16;
typedef unsigned int   u32;
typedef __attribute__((ext_vector_type(4))) float f32x4;
typedef __attribute__((ext_vector_type(4))) u16   u16x4;
typedef __attribute__((ext_vector_type(8))) __bf16 bf16x8;

#define AS1 __attribute__((address_space(1)))
#define AS3 __attribute__((address_space(3)))

__device__ __forceinline__ u16 f2bf(float f) {
  u32 u = __builtin_bit_cast(u32, f);
  u += 0x7fffu + ((u >> 16) & 1u);   // round-to-nearest-even
  return (u16)(u >> 16);
}

// ---------------- fused cast f32 -> bf16, all 8 tensors in one launch ----------------
struct Cast8 {
  const float *i0,*i1,*i2,*i3,*i4,*i5,*i6,*i7;
  u16 *o0,*o1,*o2,*o3,*o4,*o5,*o6,*o7;
};
__global__ void cast_all(Cast8 c) {
  const int i = blockIdx.x * 256 + threadIdx.x;
  if (i >= 7602176) return;
  const float* src = c.i0; u16* dst = c.o0; int off = i;
  if (i >= 2097152 && i < 4194304) { src = c.i1; dst = c.o1; off = i - 2097152; }
  if (i >= 4194304 && i < 5242880) { src = c.i2; dst = c.o2; off = i - 4194304; }
  if (i >= 5242880 && i < 5505024) { src = c.i3; dst = c.o3; off = i - 5242880; }
  if (i >= 5505024 && i < 5767168) { src = c.i4; dst = c.o4; off = i - 5505024; }
  if (i >= 5767168 && i < 6029312) { src = c.i5; dst = c.o5; off = i - 5767168; }
  if (i >= 6029312 && i < 6553600) { src = c.i6; dst = c.o6; off = i - 6029312; }
  if (i >= 6553600)                { src = c.i7; dst = c.o7; off = i - 6553600; }
  f32x4 v = *(const f32x4*)(src + (long)off * 4);
  u16x4 o = { f2bf(v[0]), f2bf(v[1]), f2bf(v[2]), f2bf(v[3]) };
  *(u16x4*)(dst + (long)off * 4) = o;
}

// chunked raster: 4-col super-columns over all Mt rows (B sub-panel L2-fit); Nt<4 -> row-major
__device__ __forceinline__ void raster(int local, int Nt, int Mt, int& ty, int& tx) {
  if (Nt < 4) { ty = local / Nt; tx = local - ty * Nt; return; }
  const int grp = local / (Mt * 4);
  const int rem = local - grp * (Mt * 4);
  ty = rem >> 2;
  tx = grp * 4 + (rem & 3);
}

// ---------------- specialized out-GEMM: m97 structure + XOR LDS swizzle ----------------
__launch_bounds__(256, 4)
__global__ void gemm_out(const u16* __restrict__ Ag, const u16* __restrict__ Bg,
                         const float* __restrict__ bias, float* __restrict__ C)
{
  __shared__ __align__(16) u16 As[128 * 64];
  __shared__ __align__(16) u16 Bs[128 * 64];
  const int id = blockIdx.x;
  const int tile = (id & 7) * 64 + (id >> 3);      // 512 tiles, bijective XCD swizzle
  int ty, tx; raster(tile, 16, 32, ty, tx);        // chunked raster (B sub-panel L2-fit)
  const int m0 = ty << 7, n0 = tx << 7;
  const int tid  = threadIdx.x;
  const int lane = tid & 63;
  const int wid  = tid >> 6;
  const int wm = wid >> 1, wn = wid & 1;
  const int lr = lane & 15, lg = lane >> 4;
  const int rmask = (lr & 7) << 3;

  f32x4 acc[4][4] = {};

  for (int k0 = 0; k0 < 2048; k0 += 64) {
    #pragma unroll
    for (int i = 0; i < 4; ++i) {
      const int eo = tid * 8 + i * 2048;
      const int r = eo >> 6;
      const int cs = (((tid & 7) ^ (r & 7)) << 3);
      __builtin_amdgcn_global_load_lds(
          (const AS1 void*)(Ag + (long)(m0 + r) * 2048 + k0 + cs),
          (AS3 void*)(As + eo), 16, 0, 0);
      __builtin_amdgcn_global_load_lds(
          (const AS1 void*)(Bg + (long)(n0 + r) * 2048 + k0 + cs),
          (AS3 void*)(Bs + eo), 16, 0, 0);
    }
    __syncthreads();
    #pragma unroll
    for (int kk = 0; kk < 64; kk += 32) {
      bf16x8 a4[4], b4[4];
      #pragma unroll
      for (int f = 0; f < 4; ++f)
        a4[f] = *(const bf16x8*)(As + (wm * 64 + f * 16 + lr) * 64 + ((kk + lg * 8) ^ rmask));
      #pragma unroll
      for (int f = 0; f < 4; ++f)
        b4[f] = *(const bf16x8*)(Bs + (wn * 64 + f * 16 + lr) * 64 + ((kk + lg * 8) ^ rmask));
      #pragma unroll
      for (int i = 0; i < 4; ++i)
        #pragma unroll
        for (int j = 0; j < 4; ++j)
          acc[i][j] = __builtin_amdgcn_mfma_f32_16x16x32_bf16(b4[j], a4[i], acc[i][j], 0, 0, 0);
    }
    __syncthreads();
  }

  #pragma unroll
  for (int i = 0; i < 4; ++i) {
    const int R = m0 + wm * 64 + i * 16 + lr;
    #pragma unroll
    for (int j = 0; j < 4; ++j) {
      const int cb = n0 + wn * 64 + j * 16 + lg * 4;
      f32x4 v = acc[i][j];
      f32x4 bv = *(const f32x4*)(bias + cb);
      v[0] += bv[0]; v[1] += bv[1]; v[2] += bv[2]; v[3] += bv[3];
      *(f32x4*)(C + (long)R * 2048 + cb) = v;
    }
  }
}

// ---------------- universal 128x128 2-phase NT GEMM + XOR LDS swizzle ----------------
// EPI: 0 f32 row-major; 1 bf16 row-major; 2 bf16 ->(B,H,S,128) swizzled d;
//      3 bf16 ->(B,H,128,S) swizzled s (scalar stores); 5 bf16 k-half (B-row remap, d=64..);
//      6 rope-fused -> k_ws d=0..63 swizzled
struct SubG {
  const u16* A; const u16* B; const float* bias; void* C;
  int Nt; int K; int lda; int ldb; int ldc; int EPI; int blk0;
};

__launch_bounds__(256, 4)
__global__ void gemm2(SubG g0, SubG g1, SubG g2, SubG g3, int ng, int nhalf)
{
  __shared__ __align__(16) u16 As[128 * 64];
  __shared__ __align__(16) u16 Bs[128 * 64];
  const int id = blockIdx.x;
  int tile = ((id & 7) * (gridDim.x >> 3)) + (id >> 3);   // bijective XCD swizzle (nwg%8==0)
  if (nhalf > 0) tile = (tile & 1) ? nhalf + (tile >> 1) : (tile >> 1);  // long/short mix
  SubG g = g0;
  if (ng > 1 && tile >= g1.blk0) g = g1;
  if (ng > 2 && tile >= g2.blk0) g = g2;
  if (ng > 3 && tile >= g3.blk0) g = g3;
  const int local = tile - g.blk0;
  int ty, tx; raster(local, g.Nt, 32, ty, tx);            // chunked raster
  const int m0 = ty << 7, n0 = tx << 7;

  const int tid  = threadIdx.x;
  const int lane = tid & 63;
  const int wid  = tid >> 6;
  const int wm = wid >> 1, wn = wid & 1;
  const int lr = lane & 15, lg = lane >> 4;
  const int lda = g.lda, ldb = g.ldb;
  const bool remapB = (g.EPI == 5);
  const u16* Ag = g.A;
  const u16* Bg = g.B;
  const int rmask = (lr & 7) << 3;

  f32x4 acc[4][4] = {};

  for (int k0 = 0; k0 < g.K; k0 += 64) {
    #pragma unroll
    for (int i = 0; i < 4; ++i) {
      const int eo = tid * 8 + i * 2048;
      const int r = eo >> 6;
      const int cs = (((tid & 7) ^ (r & 7)) << 3);
      __builtin_amdgcn_global_load_lds(
          (const AS1 void*)(Ag + (long)(m0 + r) * lda + (k0 + cs)),
          (AS3 void*)(As + eo), 16, 0, 0);
    }
    #pragma unroll
    for (int i = 0; i < 4; ++i) {
      const int eo = tid * 8 + i * 2048;
      const int r = eo >> 6;
      const int cs = (((tid & 7) ^ (r & 7)) << 3);
      int nr = n0 + r;
      if (remapB) nr = ((nr >> 6) << 7) + 64 + (nr & 63);
      __builtin_amdgcn_global_load_lds(
          (const AS1 void*)(Bg + (long)nr * ldb + (k0 + cs)),
          (AS3 void*)(Bs + eo), 16, 0, 0);
    }
    __syncthreads();
    #pragma unroll
    for (int kk = 0; kk < 64; kk += 32) {
      bf16x8 a4[4], b4[4];
      #pragma unroll
      for (int f = 0; f < 4; ++f)
        a4[f] = *(const bf16x8*)(As + (wm * 64 + f * 16 + lr) * 64 + ((kk + lg * 8) ^ rmask));
      #pragma unroll
      for (int f = 0; f < 4; ++f)
        b4[f] = *(const bf16x8*)(Bs + (wn * 64 + f * 16 + lr) * 64 + ((kk + lg * 8) ^ rmask));
      #pragma unroll
      for (int i = 0; i < 4; ++i)
        #pragma unroll
        for (int j = 0; j < 4; ++j)
          acc[i][j] = __builtin_amdgcn_mfma_f32_16x16x32_bf16(b4[j], a4[i], acc[i][j], 0, 0, 0);
    }
    __syncthreads();
  }

  // ---- epilogue (swapped layout: row = base+lr, cols = base+lg*4+{0..3})
  if (g.EPI == 6) {
    const int h = (n0 + wn * 64) >> 6;
    #pragma unroll
    for (int i = 0; i < 4; ++i) {
      const int R = m0 + wm * 64 + i * 16 + lr;
      const int b = R >> 9, s2 = R & 511;
      const long base = ((long)(b * 16 + h) * 512 + s2) << 7;
      const int msk = (s2 & 7) << 3;
      #pragma unroll
      for (int j = 0; j < 2; ++j) {
        const int cb = n0 + wn * 64 + j * 16 + lg * 4;
        f32x4 b1 = *(const f32x4*)(g.bias + cb);
        f32x4 b2 = *(const f32x4*)(g.bias + cb + 32);
        u16x4 o1, o2;
        #pragma unroll
        for (int rr = 0; rr < 4; ++rr) {
          const int ii = j * 16 + lg * 4 + rr;           // in [0,32)
          const float invf = __powf(10000.0f, -(float)ii * (1.0f / 32.0f));
          float sn, cs; __sincosf((float)s2 * invf, &sn, &cs);
          const float v1 = acc[i][j][rr] + b1[rr], v2 = acc[i][j + 2][rr] + b2[rr];
          o1[rr] = f2bf(v1 * cs - v2 * sn);
          o2[rr] = f2bf(v2 * cs + v1 * sn);
        }
        const int d1 = j * 16 + lg * 4, d2 = d1 + 32;
        *(u16x4*)((u16*)g.C + base + (d1 ^ msk)) = o1;
        *(u16x4*)((u16*)g.C + base + (d2 ^ msk)) = o2;
      }
    }
  } else {
    #pragma unroll
    for (int i = 0; i < 4; ++i) {
      const int R = m0 + wm * 64 + i * 16 + lr;
      #pragma unroll
      for (int j = 0; j < 4; ++j) {
        const int cb = n0 + wn * 64 + j * 16 + lg * 4;
        f32x4 v = acc[i][j];
        if (g.EPI == 0) {
          if (g.bias) {
            f32x4 bv = *(const f32x4*)(g.bias + cb);
            v[0] += bv[0]; v[1] += bv[1]; v[2] += bv[2]; v[3] += bv[3];
          }
          *(f32x4*)((float*)g.C + (long)R * g.ldc + cb) = v;
        } else if (g.EPI == 1) {
          f32x4 bv = *(const f32x4*)(g.bias + cb);
          u16x4 o = { f2bf(v[0] + bv[0]), f2bf(v[1] + bv[1]),
                      f2bf(v[2] + bv[2]), f2bf(v[3] + bv[3]) };
          *(u16x4*)((u16*)g.C + (long)R * g.ldc + cb) = o;
        } else if (g.EPI == 2) {
          f32x4 bv = *(const f32x4*)(g.bias + cb);
          const int b = R >> 9, s2 = R & 511, h = cb >> 7, d = cb & 127;
          u16x4 o = { f2bf(v[0] + bv[0]), f2bf(v[1] + bv[1]),
                      f2bf(v[2] + bv[2]), f2bf(v[3] + bv[3]) };
          *(u16x4*)((u16*)g.C + (((long)(b * 16 + h) * 512 + s2) << 7) + (d ^ ((s2 & 7) << 3))) = o;
        } else if (g.EPI == 5) {
          const int h = cb >> 6, d = 64 + (cb & 63);
          f32x4 bv = *(const f32x4*)(g.bias + h * 128 + d);
          const int b = R >> 9, s2 = R & 511;
          u16x4 o = { f2bf(v[0] + bv[0]), f2bf(v[1] + bv[1]),
                      f2bf(v[2] + bv[2]), f2bf(v[3] + bv[3]) };
          *(u16x4*)((u16*)g.C + (((long)(b * 16 + h) * 512 + s2) << 7) + (d ^ ((s2 & 7) << 3))) = o;
        } else { // EPI 3: 4 scalar stores (s-minor output, d varies per reg)
          const int b = R >> 9, s2 = R & 511;
          #pragma unroll
          for (int rr = 0; rr < 4; ++rr) {
            const int cc = cb + rr, h = cc >> 7, d = cc & 127;
            ((u16*)g.C)[(((long)(b * 16 + h) * 128 + d) << 9) + (s2 ^ ((d & 7) << 3))] =
                f2bf(v[rr] + g.bias[cc]);
          }
        }
      }
    }
  }
}

// ---------------- fused attention v2: K-dbuf (Qs-region reuse) + counted vmcnt +
//                  V0 prefetch + setprio. ----------------
__launch_bounds__(256, 2)
__global__ void fused_attn(const u16* __restrict__ qg, const u16* __restrict__ kg,
                           const u16* __restrict__ vg, float* __restrict__ attn,
                           u16* __restrict__ ctx)
{
  __shared__ __align__(16) u16 bufA[128 * 128];   // K tiles (even t), then V tiles
  __shared__ __align__(16) u16 bufB[128 * 128];   // Q (first 16KB) -> K tiles (odd t) -> Ps
  const int tid = threadIdx.x, lane = tid & 63, w = tid >> 6;
  const int lr = lane & 15, lg = lane >> 4;
  const int q0 = blockIdx.x * 64;
  const int bh = blockIdx.y;
  const u16* Qg = qg + ((long)bh * 512 + q0) * 128;
  const u16* Kg = kg + (long)bh * 65536;
  const u16* Vg = vg + (long)bh * 65536;

  auto stageK = [&](int t, u16* buf) {
    #pragma unroll
    for (int i = 0; i < 8; ++i)
      __builtin_amdgcn_global_load_lds((const AS1 void*)(Kg + t * 16384 + tid * 8 + i * 2048),
                                       (AS3 void*)(buf + tid * 8 + i * 2048), 16, 0, 0);
  };
  auto stageV = [&](int t) {
    #pragma unroll
    for (int i = 0; i < 8; ++i) {
      const int eo = tid * 8 + i * 2048;
      __builtin_amdgcn_global_load_lds((const AS1 void*)(Vg + (eo >> 7) * 512 + t * 128 + (eo & 127)),
                                       (AS3 void*)(bufA + eo), 16, 0, 0);
    }
  };

  #pragma unroll
  for (int i = 0; i < 4; ++i)
    __builtin_amdgcn_global_load_lds((const AS1 void*)(Qg + tid * 8 + i * 2048),
                                     (AS3 void*)(bufB + tid * 8 + i * 2048), 16, 0, 0);
  stageK(0, bufA);
  __syncthreads();

  bf16x8 qa[4];
  const int arow = 16 * w + lr;
  const int amsk = (lr & 7) << 3;
  #pragma unroll
  for (int kc = 0; kc < 4; ++kc)
    qa[kc] = *(const bf16x8*)(bufB + arow * 128 + ((kc * 32 + lg * 8) ^ amsk));
  asm volatile("s_waitcnt lgkmcnt(0)" ::: "memory");
  __builtin_amdgcn_s_barrier();                    // Qs dead -> bufB reusable
  stageK(1, bufB);

  f32x4 acc[32] = {};
  #pragma unroll
  for (int t = 0; t < 4; ++t) {
    const u16* KV = (t & 1) ? bufB : bufA;
    __builtin_amdgcn_s_setprio(1);
    #pragma unroll
    for (int nf = 0; nf < 8; ++nf) {
      const int n = nf * 16 + lr;
      const int nmsk = (n & 7) << 3;
      #pragma unroll
      for (int kc = 0; kc < 4; ++kc) {
        bf16x8 bb = *(const bf16x8*)(KV + n * 128 + ((kc * 32 + lg * 8) ^ nmsk));
        acc[t * 8 + nf] = __builtin_amdgcn_mfma_f32_16x16x32_bf16(bb, qa[kc], acc[t * 8 + nf], 0, 0, 0);
      }
    }
    __builtin_amdgcn_s_setprio(0);
    asm volatile("s_waitcnt lgkmcnt(0)" ::: "memory");
    __builtin_amdgcn_s_barrier();
    if (t < 3) {
      if (t + 2 < 4) {
        stageK(t + 2, (t & 1) ? bufB : bufA);
        asm volatile("s_waitcnt vmcnt(8)" ::: "memory");
      } else {
        asm volatile("s_waitcnt vmcnt(0)" ::: "memory");
      }
      __builtin_amdgcn_s_barrier();
      if (t == 2) stageV(0);
    }
  }

  const float scale = 0.08838834764831845f;
  float m_ = -1e30f;
  #pragma unroll
  for (int f = 0; f < 32; ++f)
    #pragma unroll
    for (int r = 0; r < 4; ++r) m_ = fmaxf(m_, acc[f][r]);
  m_ = fmaxf(m_, __shfl_xor(m_, 16));
  m_ = fmaxf(m_, __shfl_xor(m_, 32));
  float s_ = 0.f;
  #pragma unroll
  for (int f = 0; f < 32; ++f)
    #pragma unroll
    for (int r = 0; r < 4; ++r) {
      const float e = __expf((acc[f][r] - m_) * scale);
      acc[f][r] = e; s_ += e;
    }
  s_ += __shfl_xor(s_, 16);
  s_ += __shfl_xor(s_, 32);
  const float inv = 1.0f / s_;
  #pragma unroll
  for (int f = 0; f < 32; ++f)
    #pragma unroll
    for (int r = 0; r < 4; ++r) acc[f][r] *= inv;

  {
    float* arow_p = attn + ((long)bh * 512 + q0 + 16 * w + lr) * 512;
    #pragma unroll
    for (int t = 0; t < 4; ++t)
      #pragma unroll
      for (int gg = 0; gg < 8; ++gg)
        *(f32x4*)(arow_p + t * 128 + gg * 16 + lg * 4) = acc[t * 8 + gg];
  }

  f32x4 ctxa[8] = {};
  #pragma unroll
  for (int t = 0; t < 4; ++t) {
    #pragma unroll
    for (int gg = 0; gg < 8; ++gg) {
      const int col = gg * 16 + lg * 4;
      u16x4 o = { f2bf(acc[t * 8 + gg][0]), f2bf(acc[t * 8 + gg][1]),
                  f2bf(acc[t * 8 + gg][2]), f2bf(acc[t * 8 + gg][3]) };
      *(u16x4*)(bufB + arow * 128 + (col ^ amsk)) = o;
    }
    if (t > 0) stageV(t);
    __syncthreads();
    bf16x8 pa[4];
    #pragma unroll
    for (int kc = 0; kc < 4; ++kc)
      pa[kc] = *(const bf16x8*)(bufB + arow * 128 + ((kc * 32 + lg * 8) ^ amsk));
    __builtin_amdgcn_s_setprio(1);
    #pragma unroll
    for (int nf = 0; nf < 8; ++nf) {
      const int n = nf * 16 + lr;
      const int nmsk = (n & 7) << 3;
      #pragma unroll
      for (int kc = 0; kc < 4; ++kc) {
        bf16x8 vb = *(const bf16x8*)(bufA + n * 128 + ((kc * 32 + lg * 8) ^ nmsk));
        ctxa[nf] = __builtin_amdgcn_mfma_f32_16x16x32_bf16(vb, pa[kc], ctxa[nf], 0, 0, 0);
      }
    }
    __builtin_amdgcn_s_setprio(0);
    __syncthreads();
  }

  const int b = bh >> 4, h = bh & 15;
  u16* crow = ctx + (long)(b * 512 + q0 + 16 * w + lr) * 2048 + h * 128;
  #pragma unroll
  for (int nf = 0; nf < 8; ++nf) {
    u16x4 o = { f2bf(ctxa[nf][0]), f2bf(ctxa[nf][1]),
                f2bf(ctxa[nf][2]), f2bf(ctxa[nf][3]) };
    *(u16x4*)(crow + nf * 16 + lg * 4) = o;
  }
}

extern "C" void kernel_launch(void* const* d_in, const int* in_sizes, int n_in,
                              void* d_out, int out_size, void* d_ws, size_t ws_size,
                              hipStream_t stream)
{
  (void)in_sizes; (void)n_in; (void)out_size; (void)ws_size;
  const float* query  = (const float*)d_in[0];
  const float* kvin   = (const float*)d_in[1];
  const float* wq_w   = (const float*)d_in[2];
  const float* wq_b   = (const float*)d_in[3];
  const float* wdkv_w = (const float*)d_in[4];
  const float* wdkv_b = (const float*)d_in[5];
  const float* wupk_w = (const float*)d_in[6];
  const float* wupk_b = (const float*)d_in[7];
  const float* wupv_w = (const float*)d_in[8];
  const float* wupv_b = (const float*)d_in[9];
  const float* wkr_w  = (const float*)d_in[10];
  const float* wkr_b  = (const float*)d_in[11];
  const float* wo_w   = (const float*)d_in[12];
  const float* wo_b   = (const float*)d_in[13];

  float* out  = (float*)d_out;                 // (8,512,2048)
  float* attn = out + 8L * 512 * 2048;         // (8,16,512,512)

  u16* p = (u16*)d_ws;
  u16* query_bf = p; p += 8388608;
  u16* kv_bf    = p; p += 8388608;
  u16* wq_bf    = p; p += 4194304;
  u16* wdkv_bf  = p; p += 1048576;
  u16* wupk_bf  = p; p += 1048576;
  u16* wupv_bf  = p; p += 1048576;
  u16* wkr_bf   = p; p += 2097152;
  u16* wo_bf    = p; p += 4194304;
  u16* q_ws     = p; p += 8388608;   // (B,H,S,128) bf16, swizzled
  u16* ckv_bf   = p; p += 2097152;   // (4096,512) bf16
  u16* k_ws     = p; p += 8388608;   // (B,H,S,128) bf16, swizzled
  u16* vT_ws    = p; p += 8388608;   // (B,H,128,S) bf16, swizzled
  u16* ctx_ws   = p; p += 8388608;   // (B,S,H*128) bf16

  Cast8 c8 = { query, kvin, wq_w, wdkv_w, wupk_w, wupv_w, wkr_w, wo_w,
               query_bf, kv_bf, wq_bf, wdkv_bf, wupk_bf, wupv_bf, wkr_bf, wo_bf };
  cast_all<<<dim3(29696), dim3(256), 0, stream>>>(c8);

  // Launch A (all K=2048, full chip): ckv(EPI1,128t) + q(EPI2,512t) + rope(EPI6,256t)
  SubG gc = { kv_bf,    wdkv_bf, wdkv_b, ckv_bf, 4,  2048, 2048, 2048, 512, 1, 0   };
  SubG gq = { query_bf, wq_bf,   wq_b,   q_ws,   16, 2048, 2048, 2048, 0,   2, 128 };
  SubG gr = { kv_bf,    wkr_bf,  wkr_b,  k_ws,   8,  2048, 2048, 2048, 0,   6, 640 };
  gemm2<<<dim3(896), dim3(256), 0, stream>>>(gc, gq, gr, gr, 3, 0);

  // Launch B (all K=512): k_up(EPI5,256t) + v_up(EPI3,512t)   [depends on ckv_bf]
  SubG gk = { ckv_bf, wupk_bf, wupk_b, k_ws,  8,  512, 512, 512, 0, 5, 0   };
  SubG gv = { ckv_bf, wupv_bf, wupv_b, vT_ws, 16, 512, 512, 512, 0, 3, 256 };
  gemm2<<<dim3(768), dim3(256), 0, stream>>>(gk, gv, gv, gv, 2, 0);

  // fused attention: scores + softmax + attn write + PV -> ctx_ws
  fused_attn<<<dim3(8, 128, 1), 256, 0, stream>>>(q_ws, k_ws, vT_ws, attn, ctx_ws);

  // out = ctx @ wo^T + b -> f32: specialized kernel + swizzle, 512 tiles
  gemm_out<<<dim3(512), dim3(256), 0, stream>>>(ctx_ws, wo_bf, wo_b, out);
}